// Round 6
// baseline (310.827 us; speedup 1.0000x reference)
//
#include <hip/hip_runtime.h>
#include <stdint.h>

// NeRF segmented cumprod — FUSED single-pass. Each block computes its own
// chunk prefix via a backward window scan (avg segment len 256 << window
// 1024 << chunk 8192), eliminating the reduce pass entirely.
// Traffic: read 128MB + ~8MB window overlap, write 64MB  (was 256MB+64MB).
//
// Combine op (associative, NON-commutative):
//   (va,fa) (+) (vb,fb) = (fb ? vb : va*vb, fa|fb)
// Window-aggregate trick: the inclusive seg-scan aggregate of a window has
// value = product since the LAST reset in the window (exactly the prefix we
// need) and flag = "window contained a reset". Chain windows backward until
// flag set; guaranteed to terminate at g=0 (always a reset).

#define BLOCK 256
#define PT 32                    // elements per thread (blocked)
#define NV (PT / 4)              // float4/int4 vectors per thread = 8
#define CHUNK (BLOCK * PT)       // 8192 elements per block
#define NWAVE (BLOCK / 64)
#define LOOKW 1024               // backward-window elements (4 per thread)

typedef float nat_f4 __attribute__((ext_vector_type(4)));  // native vec for nontemporal

struct Pair { float v; int f; };

__device__ __forceinline__ Pair seg_combine(Pair a, Pair b) {
    Pair r;
    r.v = b.f ? b.v : (a.v * b.v);
    r.f = a.f | b.f;
    return r;
}

// alphainv default = cumprod[0] = (1-alpha[0])+1e-11 (ref: last_idx=0 for
// empty rays). Runs before the fused kernel (same stream => ordered).
__global__ void nerf_init(const float* __restrict__ alpha,
                          float* __restrict__ alphainv, int N_ray) {
    int i = blockIdx.x * blockDim.x + threadIdx.x;
    if (i < N_ray) alphainv[i] = (1.0f - alpha[0]) + 1e-11f;
}

__global__ __launch_bounds__(BLOCK, 2)
void nerf_fused(const float* __restrict__ alpha, const int* __restrict__ ray_id,
                float* __restrict__ weights, float* __restrict__ alphainv, int n) {
    __shared__ float s_wv[NWAVE];
    __shared__ int   s_wf[NWAVE];
    __shared__ int   s_rid[BLOCK];
    __shared__ float s_bv;
    __shared__ int   s_bf;

    const int c = blockIdx.x, t = threadIdx.x;
    const int lane = t & 63, w = t >> 6;
    const long bstart = (long)c * CHUNK;
    const long gstart = bstart + (long)t * PT;

    // ---- issue chunk loads early (registers) ----
    const bool full = (gstart + PT) <= (long)n;
    float4 AV[NV]; int4 RV[NV];
    if (full) {
        #pragma unroll
        for (int q = 0; q < NV; ++q) {
            AV[q] = *(const float4*)(alpha  + gstart + 4 * q);
            RV[q] = *(const int4*)  (ray_id + gstart + 4 * q);
        }
    } else {
        #pragma unroll
        for (int q = 0; q < NV; ++q) {
            float aa[4]; int rr[4];
            #pragma unroll
            for (int k = 0; k < 4; ++k) {
                long g = gstart + 4 * q + k;
                aa[k] = (g < n) ? alpha[g]  : 0.0f;
                rr[k] = (g < n) ? ray_id[g] : -2;
            }
            AV[q] = make_float4(aa[0], aa[1], aa[2], aa[3]);
            RV[q] = make_int4(rr[0], rr[1], rr[2], rr[3]);
        }
    }
    const int prev0 = (gstart > 0 && gstart < (long)n) ? ray_id[gstart - 1] : -1;

    // ---- backward-window block prefix P0 = cumprod[bstart-1] ----
    float P0 = 1.0f;
    if (c > 0) {
        long wlo = bstart - LOOKW;          // bstart >= CHUNK >= LOOKW, stays >= 0
        Pair chain; chain.v = 1.0f; chain.f = 0;
        for (;;) {
            const long e0 = wlo + 4 * t;    // always fully in-bounds: e0+3 < bstart <= n
            float4 av = *(const float4*)(alpha  + e0);
            int4   rv = *(const int4*)  (ray_id + e0);
            s_rid[t] = rv.w;
            __syncthreads();
            const int prev = (t == 0) ? ((wlo > 0) ? ray_id[wlo - 1] : -1) : s_rid[t - 1];
            Pair l;
            l.v = (1.0f - av.x) + 1e-11f; l.f = (rv.x != prev);
            { Pair e; e.v = (1.0f - av.y) + 1e-11f; e.f = (rv.y != rv.x); l = seg_combine(l, e); }
            { Pair e; e.v = (1.0f - av.z) + 1e-11f; e.f = (rv.z != rv.y); l = seg_combine(l, e); }
            { Pair e; e.v = (1.0f - av.w) + 1e-11f; e.f = (rv.w != rv.z); l = seg_combine(l, e); }
            // wave-ordered tree reduce
            #pragma unroll
            for (int off = 1; off < 64; off <<= 1) {
                Pair o;
                o.v = __shfl_down(l.v, off);
                o.f = __shfl_down(l.f, off);
                l = seg_combine(l, o);
            }
            if (lane == 0) { s_wv[w] = l.v; s_wf[w] = l.f; }
            __syncthreads();
            if (t == 0) {
                Pair acc; acc.v = s_wv[0]; acc.f = s_wf[0];
                #pragma unroll
                for (int ww = 1; ww < NWAVE; ++ww) {
                    Pair e; e.v = s_wv[ww]; e.f = s_wf[ww];
                    acc = seg_combine(acc, e);
                }
                s_bv = acc.v; s_bf = acc.f;
            }
            __syncthreads();
            Pair wagg; wagg.v = s_bv; wagg.f = s_bf;
            chain = seg_combine(wagg, chain);      // earlier (+) later
            if (chain.f || wlo == 0) break;        // g=0 is always a reset => terminates
            wlo -= LOOKW;
        }
        P0 = chain.v;
    }

    // ---- thread-local aggregate over own 32 elems ----
    Pair loc; loc.v = 1.0f; loc.f = 0;
    {
        int prev = prev0;
        #pragma unroll
        for (int q = 0; q < NV; ++q) {
            const float4 av = AV[q]; const int4 rv = RV[q];
            if (full) {
                Pair e;
                e.v = (1.0f - av.x) + 1e-11f; e.f = (rv.x != prev); loc = seg_combine(loc, e);
                e.v = (1.0f - av.y) + 1e-11f; e.f = (rv.y != rv.x); loc = seg_combine(loc, e);
                e.v = (1.0f - av.z) + 1e-11f; e.f = (rv.z != rv.y); loc = seg_combine(loc, e);
                e.v = (1.0f - av.w) + 1e-11f; e.f = (rv.w != rv.z); loc = seg_combine(loc, e);
                prev = rv.w;
            } else {
                const float aa[4] = {av.x, av.y, av.z, av.w};
                const int   rr[4] = {rv.x, rv.y, rv.z, rv.w};
                #pragma unroll
                for (int k = 0; k < 4; ++k) {
                    long g = gstart + 4 * q + k;
                    if (g < n) {
                        Pair e; e.v = (1.0f - aa[k]) + 1e-11f; e.f = (rr[k] != prev);
                        prev = rr[k];
                        loc = seg_combine(loc, e);
                    }
                }
            }
        }
    }

    // ---- wave inclusive scan over thread aggregates ----
    Pair inc = loc;
    #pragma unroll
    for (int off = 1; off < 64; off <<= 1) {
        Pair o;
        o.v = __shfl_up(inc.v, off);
        o.f = __shfl_up(inc.f, off);
        if (lane >= off) inc = seg_combine(o, inc);
    }
    Pair lexcl;
    {
        float uv = __shfl_up(inc.v, 1);
        int   uf = __shfl_up(inc.f, 1);
        if (lane == 0) { lexcl.v = 1.0f; lexcl.f = 0; }
        else           { lexcl.v = uv;   lexcl.f = uf; }
    }
    if (lane == 63) { s_wv[w] = inc.v; s_wf[w] = inc.f; }
    __syncthreads();   // also orders s_wv reuse after the window loop's last read

    Pair base; base.v = P0; base.f = (c > 0);   // flag only feeds ORs downstream
    #pragma unroll
    for (int ww = 0; ww < NWAVE; ++ww) {        // + earlier waves, in order
        if (ww < w) {
            Pair e; e.v = s_wv[ww]; e.f = s_wf[ww];
            base = seg_combine(base, e);
        }
    }
    Pair P = seg_combine(base, lexcl);          // exclusive prefix at elem 0

    // ---- apply sweep. Seg-END scatter recast as seg-START scatter:
    // at each flag (g>0), alphainv[ray_id[g-1]] = cumprod[g-1]; plus the
    // global last element writes alphainv[ray_id[n-1]] = cumprod[n-1]. ----
    {
        int prevRid = prev0;
        #pragma unroll
        for (int q = 0; q < NV; ++q) {
            const float4 av = AV[q]; const int4 rv = RV[q];
            const long e0 = gstart + 4 * q;
            if (full) {
                float w0, w1, w2, w3;
                // elem 0
                int f = (rv.x != prevRid);
                w0 = av.x * P.v;
                if (f && e0 > 0) alphainv[prevRid] = P.v;
                { Pair e; e.v = (1.0f - av.x) + 1e-11f; e.f = f; P = seg_combine(P, e); }
                if (e0 == (long)n - 1) alphainv[rv.x] = P.v;
                // elem 1
                f = (rv.y != rv.x);
                w1 = av.y * P.v;
                if (f) alphainv[rv.x] = P.v;
                { Pair e; e.v = (1.0f - av.y) + 1e-11f; e.f = f; P = seg_combine(P, e); }
                if (e0 + 1 == (long)n - 1) alphainv[rv.y] = P.v;
                // elem 2
                f = (rv.z != rv.y);
                w2 = av.z * P.v;
                if (f) alphainv[rv.y] = P.v;
                { Pair e; e.v = (1.0f - av.z) + 1e-11f; e.f = f; P = seg_combine(P, e); }
                if (e0 + 2 == (long)n - 1) alphainv[rv.z] = P.v;
                // elem 3
                f = (rv.w != rv.z);
                w3 = av.w * P.v;
                if (f) alphainv[rv.z] = P.v;
                { Pair e; e.v = (1.0f - av.w) + 1e-11f; e.f = f; P = seg_combine(P, e); }
                if (e0 + 3 == (long)n - 1) alphainv[rv.w] = P.v;

                nat_f4 wv4; wv4.x = w0; wv4.y = w1; wv4.z = w2; wv4.w = w3;
                __builtin_nontemporal_store(wv4, (nat_f4*)(weights + e0));
                prevRid = rv.w;
            } else {
                const float aa[4] = {av.x, av.y, av.z, av.w};
                const int   rr[4] = {rv.x, rv.y, rv.z, rv.w};
                #pragma unroll
                for (int k = 0; k < 4; ++k) {
                    long g = e0 + k;
                    if (g < n) {
                        int f = (rr[k] != prevRid);
                        float wv = aa[k] * P.v;
                        if (f && g > 0) alphainv[prevRid] = P.v;
                        { Pair e; e.v = (1.0f - aa[k]) + 1e-11f; e.f = f; P = seg_combine(P, e); }
                        if (g == (long)n - 1) alphainv[rr[k]] = P.v;
                        weights[g] = wv;
                        prevRid = rr[k];
                    }
                }
            }
        }
    }
}

extern "C" void kernel_launch(void* const* d_in, const int* in_sizes, int n_in,
                              void* d_out, int out_size, void* d_ws, size_t ws_size,
                              hipStream_t stream) {
    const float* alpha  = (const float*)d_in[0];
    const int*   ray_id = (const int*)d_in[1];
    const int n     = in_sizes[0];
    const int N_ray = out_size - n;          // avoids device read of d_in[2]

    float* weights  = (float*)d_out;
    float* alphainv = weights + n;

    const int nchunks = (n + CHUNK - 1) / CHUNK;

    nerf_init<<<(N_ray + BLOCK - 1) / BLOCK, BLOCK, 0, stream>>>(alpha, alphainv, N_ray);
    nerf_fused<<<nchunks, BLOCK, 0, stream>>>(alpha, ray_id, weights, alphainv, n);
}

// Round 7
// 179.334 us; speedup vs baseline: 1.7332x; 1.7332x over previous
//
#include <hip/hip_runtime.h>
#include <stdint.h>

// NeRF segmented cumprod — FUSED single-pass, STRIPED layout.
// Block prefix via backward-window scan (avg seg len 256 << LOOKW 1024 <<
// CHUNK 4096) — no second data pass. Payload uses per-wave striped 4-elem
// runs so every wave load/store instruction is a contiguous 1KB span
// (round-6 post-mortem: blocked+nontemporal stores caused 3x WRITE_SIZE
// inflation via partial-sector write-through => store-queue stalls).
//
// Combine op (associative, NON-commutative):
//   (va,fa) (+) (vb,fb) = (fb ? vb : va*vb, fa|fb)

#define BLOCK 256
#define NWAVE (BLOCK / 64)
#define NJ 4
#define WELEM (64 * 4 * NJ)      // 1024 elements per wave
#define CHUNK (NWAVE * WELEM)    // 4096 elements per block
#define LOOKW 1024               // backward-window elements (4 per thread)

struct Pair { float v; int f; };

__device__ __forceinline__ Pair seg_combine(Pair a, Pair b) {
    Pair r;
    r.v = b.f ? b.v : (a.v * b.v);
    r.f = a.f | b.f;
    return r;
}

__device__ __forceinline__ Pair wave_scan_incl(Pair x, int lane) {
    #pragma unroll
    for (int off = 1; off < 64; off <<= 1) {
        Pair o;
        o.v = __shfl_up(x.v, off);
        o.f = __shfl_up(x.f, off);
        if (lane >= off) x = seg_combine(o, x);
    }
    return x;
}

// alphainv default = cumprod[0] = (1-alpha[0])+1e-11 (ref: last_idx=0 for
// empty rays). Separate dispatch BEFORE fused kernel => no write race with
// the seg-end scatters.
__global__ void nerf_init(const float* __restrict__ alpha,
                          float* __restrict__ alphainv, int N_ray) {
    int i = blockIdx.x * blockDim.x + threadIdx.x;
    if (i < N_ray) alphainv[i] = (1.0f - alpha[0]) + 1e-11f;
}

__global__ __launch_bounds__(BLOCK, 4)
void nerf_fused(const float* __restrict__ alpha, const int* __restrict__ ray_id,
                float* __restrict__ weights, float* __restrict__ alphainv, int n) {
    __shared__ float s_wv[NWAVE];
    __shared__ int   s_wf[NWAVE];
    __shared__ int   s_rid[BLOCK];
    __shared__ float s_bv;
    __shared__ int   s_bf;

    const int c = blockIdx.x, t = threadIdx.x;
    const int lane = t & 63, w = t >> 6;
    const long bstart = (long)c * CHUNK;
    const long wbase  = bstart + (long)w * WELEM;

    // ---- Phase 1: backward-window block prefix P0 = cumprod[bstart-1] ----
    // Window aggregate's value = product since the LAST reset in the window;
    // flag = "window contains a reset". Chain backward until flag (g=0 is
    // always a reset => terminates). For this data max seg len ~330 < 1024
    // => single iteration.
    float P0 = 1.0f;
    if (c > 0) {
        long wlo = bstart - LOOKW;          // bstart >= CHUNK >= LOOKW
        Pair chain; chain.v = 1.0f; chain.f = 0;
        for (;;) {
            const long e0 = wlo + 4 * t;    // contiguous 1KB per wave
            float4 av = *(const float4*)(alpha  + e0);
            int4   rv = *(const int4*)  (ray_id + e0);
            s_rid[t] = rv.w;
            __syncthreads();
            const int prev = (t == 0) ? ((wlo > 0) ? ray_id[wlo - 1] : -1) : s_rid[t - 1];
            Pair l;
            l.v = (1.0f - av.x) + 1e-11f; l.f = (rv.x != prev);
            { Pair e; e.v = (1.0f - av.y) + 1e-11f; e.f = (rv.y != rv.x); l = seg_combine(l, e); }
            { Pair e; e.v = (1.0f - av.z) + 1e-11f; e.f = (rv.z != rv.y); l = seg_combine(l, e); }
            { Pair e; e.v = (1.0f - av.w) + 1e-11f; e.f = (rv.w != rv.z); l = seg_combine(l, e); }
            #pragma unroll
            for (int off = 1; off < 64; off <<= 1) {   // wave-ordered tree reduce
                Pair o;
                o.v = __shfl_down(l.v, off);
                o.f = __shfl_down(l.f, off);
                l = seg_combine(l, o);
            }
            if (lane == 0) { s_wv[w] = l.v; s_wf[w] = l.f; }
            __syncthreads();
            if (t == 0) {
                Pair acc; acc.v = s_wv[0]; acc.f = s_wf[0];
                #pragma unroll
                for (int ww = 1; ww < NWAVE; ++ww) {
                    Pair e; e.v = s_wv[ww]; e.f = s_wf[ww];
                    acc = seg_combine(acc, e);
                }
                s_bv = acc.v; s_bf = acc.f;
            }
            __syncthreads();
            Pair wagg; wagg.v = s_bv; wagg.f = s_bf;
            chain = seg_combine(wagg, chain);      // earlier (+) later
            if (chain.f || wlo == 0) break;
            wlo -= LOOKW;
        }
        P0 = chain.v;
    }

    // ---- Phase 2: payload sweep 1 — striped loads, per-j wave scan ----
    int last_r = -1;
    if (wbase > 0 && wbase - 1 < (long)n) last_r = ray_id[wbase - 1];

    float4 A[NJ]; int4 R[NJ]; Pair E[NJ]; int PR0[NJ];
    Pair wrun; wrun.v = 1.0f; wrun.f = 0;

    #pragma unroll
    for (int j = 0; j < NJ; ++j) {
        const long e0 = wbase + j * 256 + lane * 4;
        if (e0 + 4 <= (long)n) {
            A[j] = *(const float4*)(alpha  + e0);
            R[j] = *(const int4*)  (ray_id + e0);
        } else {
            float aa[4]; int rr[4];
            for (int k = 0; k < 4; ++k) {
                long g = e0 + k;
                aa[k] = (g < n) ? alpha[g]  : 0.0f;
                rr[k] = (g < n) ? ray_id[g] : -2;
            }
            A[j] = make_float4(aa[0], aa[1], aa[2], aa[3]);
            R[j] = make_int4(rr[0], rr[1], rr[2], rr[3]);
        }
        const float4 av = A[j]; const int4 rv = R[j];
        const bool b0 = e0 < n, b1 = e0 + 1 < n, b2 = e0 + 2 < n, b3 = e0 + 3 < n;
        const float om0 = b0 ? (1.0f - av.x) + 1e-11f : 1.0f;
        const float om1 = b1 ? (1.0f - av.y) + 1e-11f : 1.0f;
        const float om2 = b2 ? (1.0f - av.z) + 1e-11f : 1.0f;
        const float om3 = b3 ? (1.0f - av.w) + 1e-11f : 1.0f;
        const int up = __shfl_up(rv.w, 1);
        const int prev0 = (lane == 0) ? last_r : up;
        PR0[j] = prev0;
        const int f0 = b0 && (rv.x != prev0);
        const int f1 = b1 && (rv.y != rv.x);
        const int f2 = b2 && (rv.z != rv.y);
        const int f3 = b3 && (rv.w != rv.z);

        Pair l; l.v = om0; l.f = f0;
        { Pair e; e.v = om1; e.f = f1; l = seg_combine(l, e); }
        { Pair e; e.v = om2; e.f = f2; l = seg_combine(l, e); }
        { Pair e; e.v = om3; e.f = f3; l = seg_combine(l, e); }

        Pair ws = wave_scan_incl(l, lane);
        Pair wse;
        {   // lane-exclusive within wave
            float uv = __shfl_up(ws.v, 1);
            int   uf = __shfl_up(ws.f, 1);
            if (lane == 0) { wse.v = 1.0f; wse.f = 0; }
            else           { wse.v = uv;   wse.f = uf; }
        }
        E[j] = seg_combine(wrun, wse);     // within-wave prefix before (j, lane)
        Pair jag; jag.v = __shfl(ws.v, 63); jag.f = __shfl(ws.f, 63);
        wrun = seg_combine(wrun, jag);
        last_r = __shfl(rv.w, 63);
    }

    if (lane == 0) { s_wv[w] = wrun.v; s_wf[w] = wrun.f; }
    __syncthreads();   // safe: all window-phase LDS reads happened before the
                       // loop's final __syncthreads for every thread

    Pair base; base.v = P0; base.f = (c > 0);     // flag only feeds ORs downstream
    for (int ww = 0; ww < w; ++ww) {              // + earlier waves, in order
        Pair e; e.v = s_wv[ww]; e.f = s_wf[ww];
        base = seg_combine(base, e);
    }

    // ---- Phase 3: apply sweep — striped 1KB wave stores, seg-START scatter:
    // at each flag (g>0), alphainv[ray_id[g-1]] = cumprod[g-1]; plus global
    // last element writes alphainv[ray_id[n-1]] = cumprod[n-1]. ----
    #pragma unroll
    for (int j = 0; j < NJ; ++j) {
        Pair P = seg_combine(base, E[j]);         // exclusive prefix at elem 0
        const float4 av = A[j]; const int4 rv = R[j];
        const long e0 = wbase + j * 256 + lane * 4;
        const bool b0 = e0 < n, b1 = e0 + 1 < n, b2 = e0 + 2 < n, b3 = e0 + 3 < n;
        const float om0 = b0 ? (1.0f - av.x) + 1e-11f : 1.0f;
        const float om1 = b1 ? (1.0f - av.y) + 1e-11f : 1.0f;
        const float om2 = b2 ? (1.0f - av.z) + 1e-11f : 1.0f;
        const float om3 = b3 ? (1.0f - av.w) + 1e-11f : 1.0f;
        const int prev0 = PR0[j];
        const int f0 = b0 && (rv.x != prev0);
        const int f1 = b1 && (rv.y != rv.x);
        const int f2 = b2 && (rv.z != rv.y);
        const int f3 = b3 && (rv.w != rv.z);

        float w0, w1, w2, w3;
        // elem 0
        w0 = av.x * P.v;
        if (f0 && e0 > 0) alphainv[prev0] = P.v;
        { Pair e; e.v = om0; e.f = f0; P = seg_combine(P, e); }
        if (b0 && e0 == (long)n - 1) alphainv[rv.x] = P.v;
        // elem 1
        w1 = av.y * P.v;
        if (f1) alphainv[rv.x] = P.v;
        { Pair e; e.v = om1; e.f = f1; P = seg_combine(P, e); }
        if (b1 && e0 + 1 == (long)n - 1) alphainv[rv.y] = P.v;
        // elem 2
        w2 = av.z * P.v;
        if (f2) alphainv[rv.y] = P.v;
        { Pair e; e.v = om2; e.f = f2; P = seg_combine(P, e); }
        if (b2 && e0 + 2 == (long)n - 1) alphainv[rv.z] = P.v;
        // elem 3
        w3 = av.w * P.v;
        if (f3) alphainv[rv.z] = P.v;
        { Pair e; e.v = om3; e.f = f3; P = seg_combine(P, e); }
        if (b3 && e0 + 3 == (long)n - 1) alphainv[rv.w] = P.v;

        if (e0 + 4 <= (long)n) {
            *(float4*)(weights + e0) = make_float4(w0, w1, w2, w3);
        } else {
            float ww4[4] = {w0, w1, w2, w3};
            for (int k = 0; k < 4; ++k) {
                long g = e0 + k;
                if (g < n) weights[g] = ww4[k];
            }
        }
    }
}

extern "C" void kernel_launch(void* const* d_in, const int* in_sizes, int n_in,
                              void* d_out, int out_size, void* d_ws, size_t ws_size,
                              hipStream_t stream) {
    const float* alpha  = (const float*)d_in[0];
    const int*   ray_id = (const int*)d_in[1];
    const int n     = in_sizes[0];
    const int N_ray = out_size - n;          // avoids device read of d_in[2]

    float* weights  = (float*)d_out;
    float* alphainv = weights + n;

    const int nchunks = (n + CHUNK - 1) / CHUNK;

    nerf_init<<<(N_ray + BLOCK - 1) / BLOCK, BLOCK, 0, stream>>>(alpha, alphainv, N_ray);
    nerf_fused<<<nchunks, BLOCK, 0, stream>>>(alpha, ray_id, weights, alphainv, n);
}

// Round 8
// 175.585 us; speedup vs baseline: 1.7702x; 1.0214x over previous
//
#include <hip/hip_runtime.h>
#include <stdint.h>

// NeRF segmented cumprod — FUSED single-pass, STRIPED layout, SIGN-ENCODED
// segmented-scan state. (value,flag) pair packed into one float: x = f?-v:v
// (valid: all values > 0; IEEE (-x)*y = -(x*y) exactly; FTZ keeps -0 sign;
// flag test = integer sign test, so -0 still reads flagged).
//   comb(a,b) = (bits(b)<0) ? b : a*b      == (fb ? vb : va*vb, fa|fb)
// Halves the shuffle count per scan step vs (v,f) pairs.
//
// Block prefix via backward-window scan (avg seg len 256; window 256 =>
// expected ~1.6 iterations), computed redundantly per-wave => ZERO barriers
// in the window phase. One __syncthreads per block total.

#define BLOCK 256
#define NWAVE (BLOCK / 64)
#define NJ 4
#define WELEM (64 * 4 * NJ)      // 1024 elements per wave
#define CHUNK (NWAVE * WELEM)    // 4096 elements per block
#define WIN 256                  // backward-window elements per iteration

__device__ __forceinline__ float comb(float a, float b) {
    // segmented-product combine on sign-encoded operands
    return (__float_as_int(b) < 0) ? b : a * b;
}

// alphainv default = cumprod[0] = (1-alpha[0])+1e-11 (ref: last_idx=0 for
// empty rays). Separate dispatch BEFORE fused kernel => ordered, no race.
__global__ void nerf_init(const float* __restrict__ alpha,
                          float* __restrict__ alphainv, int N_ray) {
    int i = blockIdx.x * blockDim.x + threadIdx.x;
    if (i < N_ray) alphainv[i] = (1.0f - alpha[0]) + 1e-11f;
}

__global__ __launch_bounds__(BLOCK, 4)
void nerf_fused(const float* __restrict__ alpha, const int* __restrict__ ray_id,
                float* __restrict__ weights, float* __restrict__ alphainv, int n) {
    __shared__ float s_wv[NWAVE];

    const int c = blockIdx.x, t = threadIdx.x;
    const int lane = t & 63, w = t >> 6;
    const long bstart = (long)c * CHUNK;
    const long wbase  = bstart + (long)w * WELEM;

    // ---- issue window iter-0 loads FIRST (they head the critical path) ----
    long wlo = bstart - WIN;                 // c>0 => bstart>=CHUNK>=WIN
    float4 wav; int4 wrv;
    if (c > 0) {
        wav = *(const float4*)(alpha  + wlo + lane * 4);
        wrv = *(const int4*)  (ray_id + wlo + lane * 4);
    }

    // ---- payload loads (independent; fill the memory pipe) ----
    float4 A[NJ]; int4 R[NJ];
    #pragma unroll
    for (int j = 0; j < NJ; ++j) {
        const long e0 = wbase + (long)j * 256 + lane * 4;
        if (e0 + 4 <= (long)n) {
            A[j] = *(const float4*)(alpha  + e0);
            R[j] = *(const int4*)  (ray_id + e0);
        } else {
            float aa[4]; int rr[4];
            #pragma unroll
            for (int k = 0; k < 4; ++k) {
                long g = e0 + k;
                aa[k] = (g < n) ? alpha[g]  : 0.0f;
                rr[k] = (g < n) ? ray_id[g] : -2;
            }
            A[j] = make_float4(aa[0], aa[1], aa[2], aa[3]);
            R[j] = make_int4(rr[0], rr[1], rr[2], rr[3]);
        }
    }
    int last_r = -1;
    if (wbase > 0 && wbase - 1 < (long)n) last_r = ray_id[wbase - 1];

    // ---- Phase 1: backward-window block prefix, PER-WAVE redundant,
    //      zero barriers. Window aggregate value = product since the last
    //      reset in the window; sign = "window contained a reset". Chain
    //      backward until flagged (g=0 always flags => terminates). ----
    float P0 = 1.0f;
    if (c > 0) {
        float chain = 1.0f;
        for (;;) {
            int pw = __shfl_up(wrv.w, 1);
            if (lane == 0) pw = (wlo > 0) ? ray_id[wlo - 1] : -1;
            const float om0 = (1.0f - wav.x) + 1e-11f;
            const float om1 = (1.0f - wav.y) + 1e-11f;
            const float om2 = (1.0f - wav.z) + 1e-11f;
            const float om3 = (1.0f - wav.w) + 1e-11f;
            const float s0 = (wrv.x != pw)    ? -om0 : om0;
            const float s1 = (wrv.y != wrv.x) ? -om1 : om1;
            const float s2 = (wrv.z != wrv.y) ? -om2 : om2;
            const float s3 = (wrv.w != wrv.z) ? -om3 : om3;
            float l = comb(comb(comb(s0, s1), s2), s3);
            #pragma unroll
            for (int off = 1; off < 64; off <<= 1) {   // wave-ordered reduce
                float o = __shfl_down(l, off);
                l = comb(l, o);
            }
            float wagg = __shfl(l, 0);
            chain = comb(wagg, chain);                 // earlier (+) later
            if (__float_as_int(chain) < 0 || wlo == 0) break;
            wlo -= WIN;
            wav = *(const float4*)(alpha  + wlo + lane * 4);
            wrv = *(const int4*)  (ray_id + wlo + lane * 4);
        }
        P0 = chain;      // encoded: sign carries the (always-set) flag
    }

    // ---- Phase 2: per-j wave scans over payload (1 shuffle per step) ----
    float E[NJ]; int PR0[NJ];
    float wrun = 1.0f;
    #pragma unroll
    for (int j = 0; j < NJ; ++j) {
        const long e0 = wbase + (long)j * 256 + lane * 4;
        const float4 av = A[j]; const int4 rv = R[j];
        const bool b0 = e0 < n, b1 = e0 + 1 < n, b2 = e0 + 2 < n, b3 = e0 + 3 < n;
        const float om0 = b0 ? (1.0f - av.x) + 1e-11f : 1.0f;
        const float om1 = b1 ? (1.0f - av.y) + 1e-11f : 1.0f;
        const float om2 = b2 ? (1.0f - av.z) + 1e-11f : 1.0f;
        const float om3 = b3 ? (1.0f - av.w) + 1e-11f : 1.0f;
        int pw = __shfl_up(rv.w, 1);
        const int prev0 = (lane == 0) ? last_r : pw;
        PR0[j] = prev0;
        const float s0 = (b0 && rv.x != prev0) ? -om0 : om0;
        const float s1 = (b1 && rv.y != rv.x)  ? -om1 : om1;
        const float s2 = (b2 && rv.z != rv.y)  ? -om2 : om2;
        const float s3 = (b3 && rv.w != rv.z)  ? -om3 : om3;
        float l = comb(comb(comb(s0, s1), s2), s3);

        float ws = l;                                   // wave inclusive scan
        #pragma unroll
        for (int off = 1; off < 64; off <<= 1) {
            float o = __shfl_up(ws, off);
            if (lane >= off) ws = comb(o, ws);
        }
        float wse = __shfl_up(ws, 1);                   // lane-exclusive
        if (lane == 0) wse = 1.0f;
        E[j] = comb(wrun, wse);                         // prefix before (j,lane)
        wrun = comb(wrun, __shfl(ws, 63));
        last_r = __shfl(rv.w, 63);
    }

    if (lane == 0) s_wv[w] = wrun;
    __syncthreads();                                    // the ONLY barrier

    float base = P0;                                    // identity 1.0 if c==0
    for (int ww = 0; ww < w; ++ww) base = comb(base, s_wv[ww]);

    // ---- Phase 3: apply + stores. Seg-START scatter: at each flag (g>0),
    // alphainv[ray_id[g-1]] = cumprod[g-1]; plus the global last element
    // writes alphainv[ray_id[n-1]] = cumprod[n-1]. ----
    #pragma unroll
    for (int j = 0; j < NJ; ++j) {
        float P = comb(base, E[j]);                     // encoded excl prefix
        const float4 av = A[j]; const int4 rv = R[j];
        const long e0 = wbase + (long)j * 256 + lane * 4;
        const bool b0 = e0 < n, b1 = e0 + 1 < n, b2 = e0 + 2 < n, b3 = e0 + 3 < n;
        const float om0 = b0 ? (1.0f - av.x) + 1e-11f : 1.0f;
        const float om1 = b1 ? (1.0f - av.y) + 1e-11f : 1.0f;
        const float om2 = b2 ? (1.0f - av.z) + 1e-11f : 1.0f;
        const float om3 = b3 ? (1.0f - av.w) + 1e-11f : 1.0f;
        const int prev0 = PR0[j];
        const int f0 = b0 && (rv.x != prev0);
        const int f1 = b1 && (rv.y != rv.x);
        const int f2 = b2 && (rv.z != rv.y);
        const int f3 = b3 && (rv.w != rv.z);

        float w0, w1, w2, w3, trans;
        // elem 0
        trans = fabsf(P);
        w0 = av.x * trans;
        if (f0 && e0 > 0) alphainv[prev0] = trans;
        P = comb(P, f0 ? -om0 : om0);
        if (b0 && e0 == (long)n - 1) alphainv[rv.x] = fabsf(P);
        // elem 1
        trans = fabsf(P);
        w1 = av.y * trans;
        if (f1) alphainv[rv.x] = trans;
        P = comb(P, f1 ? -om1 : om1);
        if (b1 && e0 + 1 == (long)n - 1) alphainv[rv.y] = fabsf(P);
        // elem 2
        trans = fabsf(P);
        w2 = av.z * trans;
        if (f2) alphainv[rv.y] = trans;
        P = comb(P, f2 ? -om2 : om2);
        if (b2 && e0 + 2 == (long)n - 1) alphainv[rv.z] = fabsf(P);
        // elem 3
        trans = fabsf(P);
        w3 = av.w * trans;
        if (f3) alphainv[rv.z] = trans;
        P = comb(P, f3 ? -om3 : om3);
        if (b3 && e0 + 3 == (long)n - 1) alphainv[rv.w] = fabsf(P);

        if (e0 + 4 <= (long)n) {
            *(float4*)(weights + e0) = make_float4(w0, w1, w2, w3);
        } else {
            float ww4[4] = {w0, w1, w2, w3};
            for (int k = 0; k < 4; ++k) {
                long g = e0 + k;
                if (g < n) weights[g] = ww4[k];
            }
        }
    }
}

extern "C" void kernel_launch(void* const* d_in, const int* in_sizes, int n_in,
                              void* d_out, int out_size, void* d_ws, size_t ws_size,
                              hipStream_t stream) {
    const float* alpha  = (const float*)d_in[0];
    const int*   ray_id = (const int*)d_in[1];
    const int n     = in_sizes[0];
    const int N_ray = out_size - n;          // avoids device read of d_in[2]

    float* weights  = (float*)d_out;
    float* alphainv = weights + n;

    const int nchunks = (n + CHUNK - 1) / CHUNK;

    nerf_init<<<(N_ray + BLOCK - 1) / BLOCK, BLOCK, 0, stream>>>(alpha, alphainv, N_ray);
    nerf_fused<<<nchunks, BLOCK, 0, stream>>>(alpha, ray_id, weights, alphainv, n);
}